// Round 2
// baseline (374.815 us; speedup 1.0000x reference)
//
#include <hip/hip_runtime.h>
#include <hip/hip_fp16.h>

// Fused MSE + SSIM loss, 32x3x512x512 fp32, MI355X — R6.
// R5 counters: VALUBusy 71%, HBM 25%, MfmaUtil 0, occupancy 53% -> structure/latency
// bound, not issue-bound. Two structural losses fixed:
//  (1) Persistent column strips: block owns 64x256 px, sweeps down in 32-row chunks
//      with a 48-row circular LDS window of horizontal-pass output.
//      Vertical halo recompute 1.31x -> 1.04x (266 h-rows per 256 out rows).
//  (2) Steady-state stage-A passes are exactly 256 items / 256 threads (perfect
//      balance; R5 had wall=2 items for avg 1.31).
//  Grid 8x2x96 = 1536 blocks = exactly 6/CU (LDS 24.6KB -> 6 resident).
//  Finalize merged via atomic-counter last-block pattern (one less launch).
// Math identical to R5: S/D algebra (4 half2 fields), packed-fp16 conv both passes.

#define WSZ   512
#define TW    64
#define GX    (WSZ / TW)       // 8
#define HH    256              // output rows per block
#define CH    32               // chunk rows
#define NCH   (HH / CH)        // 8
#define BUF   48               // circular LDS row window
#define NPOS  32               // float4 slots per row
#define HALO  5
#define NSLOT 64
#define SSIM_C1 0.0001f
#define SSIM_C2 0.0009f

// 11-tap gaussian, sigma=1.5, normalized
#define W0 0.00102838f
#define W1 0.00759876f
#define W2 0.03600080f
#define W3 0.10936080f
#define W4 0.21300560f
#define W5 0.26601170f

static __device__ __forceinline__ __half2 pk(float a, float b) {
    return __builtin_bit_cast(__half2, __builtin_amdgcn_cvt_pkrtz(a, b));
}
// staggered pair: (lo.hi, hi.lo) == (x[2u+1], x[2u+2])
static __device__ __forceinline__ __half2 stagger(__half2 hi, __half2 lo) {
    return __builtin_bit_cast(__half2,
        __builtin_amdgcn_alignbit(__builtin_bit_cast(unsigned, hi),
                                  __builtin_bit_cast(unsigned, lo), 16));
}

__launch_bounds__(256, 6)
__global__ void fused_mse_ssim(const float* __restrict__ P,
                               const float* __restrict__ T,
                               float* __restrict__ ws,
                               float* __restrict__ out,
                               float invN, int nblocks) {
    __shared__ float4 sAB[BUF][NPOS];   // fields per slot: S, D, SS, DD (half2)
    __shared__ float  red[2][4];
    __shared__ int    sLast;

    const int tid = threadIdx.x;
    const int gx0 = blockIdx.x * TW;
    const int gyb = blockIdx.y * HH;                // 0 or 256
    const size_t plane = (size_t)blockIdx.z * (WSZ * (size_t)WSZ);
    const float* Pp = P + plane;
    const float* Tp = T + plane;
    const bool xedge = (blockIdx.x == 0) || (blockIdx.x == GX - 1);

    const float gwf[11] = {W0,W1,W2,W3,W4,W5,W4,W3,W2,W1,W0};
    unsigned gwh[11];   // half2(w,w) bit patterns, wave-uniform -> SGPR
    #pragma unroll
    for (int k = 0; k < 11; ++k)
        gwh[k] = __builtin_amdgcn_readfirstlane(
                     __builtin_bit_cast(unsigned, __float2half2_rn(gwf[k])));

    float mse = 0.f;
    float ssim = 0.f;

    for (int c = 0; c < NCH; ++c) {
        // ---- stage A pass c: horizontal 11-tap on S,D,S^2,D^2 (packed fp16).
        // pass 0: lr 0..41 (42 rows); pass c>=1: lr c*32+10 .. c*32+41 (32 rows).
        const int nIt = (c == 0) ? 42 * 8 : 32 * 8;
        const int lrb = (c == 0) ? 0 : c * CH + 2 * HALO;
        for (int it = tid; it < nIt; it += 256) {
            const int r    = it >> 3;
            const int q    = it & 7;
            const int lr   = lrb + r;               // local h-row index, 0..265
            const int gy   = gyb + lr - HALO;       // global image row
            const int slot = lr % BUF;
            const bool rv   = ((unsigned)gy < (unsigned)WSZ);
            const bool mrow = ((unsigned)(lr - HALO) < (unsigned)HH); // owned row
            const int cb = gx0 + q * 8 - 8;         // leftmost loaded px (16B aligned)
            const float* prow = Pp + ((long)gy * WSZ + cb);
            const float* trow = Tp + ((long)gy * WSZ + cb);

            const __half2 z = __float2half2_rn(0.f);
            __half2 As[12], Ad[12];

            if (!xedge) {
                if (rv) {
                    #pragma unroll
                    for (int b = 0; b < 6; ++b) {
                        const float4 pv = *(const float4*)(prow + 4 * b);
                        const float4 tv = *(const float4*)(trow + 4 * b);
                        const float s0 = pv.x + tv.x, s1 = pv.y + tv.y;
                        const float s2 = pv.z + tv.z, s3 = pv.w + tv.w;
                        const float d0 = pv.x - tv.x, d1 = pv.y - tv.y;
                        const float d2 = pv.z - tv.z, d3 = pv.w - tv.w;
                        As[2*b]   = pk(s0, s1); As[2*b+1] = pk(s2, s3);
                        Ad[2*b]   = pk(d0, d1); Ad[2*b+1] = pk(d2, d3);
                        if ((b == 2 || b == 3) && mrow) {
                            mse = fmaf(d0, d0, mse); mse = fmaf(d1, d1, mse);
                            mse = fmaf(d2, d2, mse); mse = fmaf(d3, d3, mse);
                        }
                    }
                } else {
                    #pragma unroll
                    for (int b = 0; b < 12; ++b) { As[b] = z; Ad[b] = z; }
                }
            } else {
                #pragma unroll
                for (int b = 0; b < 6; ++b) {
                    const unsigned cc = (unsigned)(cb + 4 * b);
                    float4 pv = make_float4(0.f, 0.f, 0.f, 0.f);
                    float4 tv = make_float4(0.f, 0.f, 0.f, 0.f);
                    if (rv && cc < (unsigned)WSZ) {
                        pv = *(const float4*)(prow + 4 * b);
                        tv = *(const float4*)(trow + 4 * b);
                    }
                    const float s0 = pv.x + tv.x, s1 = pv.y + tv.y;
                    const float s2 = pv.z + tv.z, s3 = pv.w + tv.w;
                    const float d0 = pv.x - tv.x, d1 = pv.y - tv.y;
                    const float d2 = pv.z - tv.z, d3 = pv.w - tv.w;
                    As[2*b]   = pk(s0, s1); As[2*b+1] = pk(s2, s3);
                    Ad[2*b]   = pk(d0, d1); Ad[2*b+1] = pk(d2, d3);
                    if ((b == 2 || b == 3) && mrow) {
                        mse = fmaf(d0, d0, mse); mse = fmaf(d1, d1, mse);
                        mse = fmaf(d2, d2, mse); mse = fmaf(d3, d3, mse);
                    }
                }
            }

            // packed conv: output pair m (=out px 2m,2m+1) needs px[3+2m+k], k=0..10
            __half2 aS[4]  = {z, z, z, z};
            __half2 aD[4]  = {z, z, z, z};
            __half2 aSS[4] = {z, z, z, z};
            __half2 aDD[4] = {z, z, z, z};

            #pragma unroll
            for (int jj = 0; jj <= 16; ++jj) {
                const int j = jj + 3;
                __half2 vs, vd;
                if (j & 1) {
                    vs = stagger(As[(j >> 1) + 1], As[j >> 1]);
                    vd = stagger(Ad[(j >> 1) + 1], Ad[j >> 1]);
                } else {
                    vs = As[j >> 1];
                    vd = Ad[j >> 1];
                }
                const __half2 vss = __hmul2(vs, vs);
                const __half2 vdd = __hmul2(vd, vd);
                #pragma unroll
                for (int m = 0; m < 4; ++m) {
                    const int k = jj - 2 * m;
                    if (k >= 0 && k < 11) {
                        const __half2 w = __builtin_bit_cast(__half2, gwh[k]);
                        aS[m]  = __hfma2(w, vs,  aS[m]);
                        aD[m]  = __hfma2(w, vd,  aD[m]);
                        aSS[m] = __hfma2(w, vss, aSS[m]);
                        aDD[m] = __hfma2(w, vdd, aDD[m]);
                    }
                }
            }

            // slot-spread store: position pos=4q+m lives at col 8m+q
            #pragma unroll
            for (int m = 0; m < 4; ++m)
                sAB[slot][8 * m + q] = make_float4(
                    __builtin_bit_cast(float, aS[m]),  __builtin_bit_cast(float, aD[m]),
                    __builtin_bit_cast(float, aSS[m]), __builtin_bit_cast(float, aDD[m]));
        }
        __syncthreads();

        // ---- stage B chunk c: vertical 11-tap (packed fp16), 4 out rows/thread
        {
            const int q2  = tid & 31;
            const int col = ((q2 & 3) << 3) | (q2 >> 2);     // un-permute storage col
            const int y0l = c * CH + ((tid >> 5) << 2);      // local lr base of window
            const int s0  = y0l % BUF;

            const __half2 z2 = __float2half2_rn(0.f);
            __half2 acc[4][4];
            #pragma unroll
            for (int a = 0; a < 4; ++a) {
                acc[a][0] = z2; acc[a][1] = z2; acc[a][2] = z2; acc[a][3] = z2;
            }

            #pragma unroll
            for (int j = 0; j < 14; ++j) {                   // window rows y0l..y0l+13
                int s = s0 + j; if (s >= BUF) s -= BUF;
                const float4 ab = sAB[s][col];
                const __half2 hS  = __builtin_bit_cast(__half2, ab.x);
                const __half2 hD  = __builtin_bit_cast(__half2, ab.y);
                const __half2 hSS = __builtin_bit_cast(__half2, ab.z);
                const __half2 hDD = __builtin_bit_cast(__half2, ab.w);
                #pragma unroll
                for (int a = 0; a < 4; ++a) {
                    const int k = j - a;
                    if (k >= 0 && k < 11) {
                        const __half2 w = __builtin_bit_cast(__half2, gwh[k]);
                        acc[a][0] = __hfma2(w, hS,  acc[a][0]);
                        acc[a][1] = __hfma2(w, hD,  acc[a][1]);
                        acc[a][2] = __hfma2(w, hSS, acc[a][2]);
                        acc[a][3] = __hfma2(w, hDD, acc[a][3]);
                    }
                }
            }

            // SSIM epilogue (fp32), S/D algebra:
            //   2mu12+C1 = 0.5(A^2-B^2)+C1 ; mu1^2+mu2^2+C1 = 0.5(A^2+B^2)+C1
            //   2s12+C2  = 0.5((X-Y)-(A^2-B^2))+C2 ; s1+s2+C2 = 0.5((X+Y)-(A^2+B^2))+C2
            #pragma unroll
            for (int a = 0; a < 4; ++a) {
                const float2 Av = __half22float2(acc[a][0]);
                const float2 Bv = __half22float2(acc[a][1]);
                const float2 Xv = __half22float2(acc[a][2]);
                const float2 Yv = __half22float2(acc[a][3]);
                #pragma unroll
                for (int e = 0; e < 2; ++e) {
                    const float A = e ? Av.y : Av.x;
                    const float B = e ? Bv.y : Bv.x;
                    const float X = e ? Xv.y : Xv.x;
                    const float Y = e ? Yv.y : Yv.x;
                    const float a2 = A * A;
                    const float b2 = B * B;
                    const float P1 = a2 + b2;
                    const float M1 = a2 - b2;
                    const float num1 = fmaf(0.5f, M1, SSIM_C1);
                    const float den1 = fmaf(0.5f, P1, SSIM_C1);
                    const float num2 = fmaf(0.5f, (X - Y) - M1, SSIM_C2);
                    const float den2 = fmaf(0.5f, (X + Y) - P1, SSIM_C2);
                    ssim = fmaf(num1 * num2, __builtin_amdgcn_rcpf(den1 * den2), ssim);
                }
            }
        }
        __syncthreads();
    }

    // ---- reduction: wave shuffle -> LDS -> 2 atomics -> last-block finalize ----
    #pragma unroll
    for (int off = 32; off > 0; off >>= 1) {
        mse  += __shfl_down(mse, off);
        ssim += __shfl_down(ssim, off);
    }
    const int wid = tid >> 6;
    if ((tid & 63) == 0) { red[0][wid] = mse; red[1][wid] = ssim; }
    __syncthreads();
    if (tid == 0) {
        const float m = red[0][0] + red[0][1] + red[0][2] + red[0][3];
        const float s = red[1][0] + red[1][1] + red[1][2] + red[1][3];
        const int bid  = (blockIdx.z * gridDim.y + blockIdx.y) * gridDim.x + blockIdx.x;
        const int slot = (bid & (NSLOT - 1)) * 16;     // 64B apart
        atomicAdd(&ws[slot + 0], m);
        atomicAdd(&ws[slot + 1], s);
        __threadfence();
        const unsigned old = __hip_atomic_fetch_add(
            (unsigned*)(ws + NSLOT * 16), 1u,
            __ATOMIC_ACQ_REL, __HIP_MEMORY_SCOPE_AGENT);
        sLast = (old == (unsigned)(nblocks - 1)) ? 1 : 0;
    }
    __syncthreads();
    if (sLast && tid < 64) {
        float m = __hip_atomic_load(&ws[tid * 16 + 0], __ATOMIC_ACQUIRE,
                                    __HIP_MEMORY_SCOPE_AGENT);
        float s = __hip_atomic_load(&ws[tid * 16 + 1], __ATOMIC_ACQUIRE,
                                    __HIP_MEMORY_SCOPE_AGENT);
        #pragma unroll
        for (int off = 32; off > 0; off >>= 1) {
            m += __shfl_down(m, off);
            s += __shfl_down(s, off);
        }
        if (tid == 0) out[0] = m * invN + 0.01f * (1.f - s * invN);
    }
}

extern "C" void kernel_launch(void* const* d_in, const int* in_sizes, int n_in,
                              void* d_out, int out_size, void* d_ws, size_t ws_size,
                              hipStream_t stream) {
    const float* P = (const float*)d_in[0];
    const float* T = (const float*)d_in[1];
    float* out = (float*)d_out;
    float* ws  = (float*)d_ws;

    const int planes  = in_sizes[0] / (WSZ * WSZ);     // 96
    const float invN  = 1.f / (float)in_sizes[0];
    const int nblocks = GX * 2 * planes;               // 1536

    (void)hipMemsetAsync(ws, 0, (NSLOT * 16 + 16) * sizeof(float), stream);
    dim3 grid(GX, 2, planes);
    fused_mse_ssim<<<grid, 256, 0, stream>>>(P, T, ws, out, invN, nblocks);
}